// Round 1
// baseline (1393.196 us; speedup 1.0000x reference)
//
#include <hip/hip_runtime.h>
#include <hip/hip_bf16.h>

// ---- problem constants ----
#define E_NUM 16
#define TOPK 4
#define H_DIM 2048
#define I_DIM 1408
#define IS_DIM 5632
#define M_TOK 4096

typedef __attribute__((ext_vector_type(8))) short short8;
typedef __attribute__((ext_vector_type(4))) float f32x4;

static __device__ __forceinline__ unsigned short f2bf(float f) {
    unsigned int u = __float_as_uint(f);
    unsigned int r = (u + 0x7FFFu + ((u >> 16) & 1u)) >> 16;
    return (unsigned short)r;
}

// ---------------- router: fp32 logits, softmax, top-4, shared gate ----------------
__global__ __launch_bounds__(256) void k_router(
    const float* __restrict__ x, const float* __restrict__ gw,
    const float* __restrict__ sgw, int* __restrict__ counts,
    int* __restrict__ ltok, float* __restrict__ lcoef, float* __restrict__ sg)
{
    const int wid = threadIdx.x >> 6, lane = threadIdx.x & 63;
    const int t = blockIdx.x * 4 + wid;
    const float* xr = x + (size_t)t * H_DIM;
    float xv[32];
#pragma unroll
    for (int i = 0; i < 32; ++i) xv[i] = xr[i * 64 + lane];

    float lg[E_NUM];
    for (int e = 0; e < E_NUM; ++e) {
        const float* g = gw + (size_t)e * H_DIM;
        float s = 0.f;
#pragma unroll
        for (int i = 0; i < 32; ++i) s += xv[i] * g[i * 64 + lane];
#pragma unroll
        for (int off = 32; off; off >>= 1) s += __shfl_xor(s, off);
        lg[e] = s;
    }
    {   // shared expert gate (sigmoid)
        float s = 0.f;
#pragma unroll
        for (int i = 0; i < 32; ++i) s += xv[i] * sgw[i * 64 + lane];
#pragma unroll
        for (int off = 32; off; off >>= 1) s += __shfl_xor(s, off);
        if (lane == 0) sg[t] = 1.f / (1.f + __expf(-s));
    }
    // softmax (fp32, redundant on all lanes)
    float mx = lg[0];
#pragma unroll
    for (int e = 1; e < E_NUM; ++e) mx = fmaxf(mx, lg[e]);
    float sum = 0.f, w[E_NUM];
#pragma unroll
    for (int e = 0; e < E_NUM; ++e) { w[e] = __expf(lg[e] - mx); sum += w[e]; }
    float inv = 1.f / sum;
#pragma unroll
    for (int e = 0; e < E_NUM; ++e) w[e] *= inv;

    if (lane == 0) {
        for (int j = 0; j < TOPK; ++j) {
            float best = -1.f; int bi = 0;
            for (int e = 0; e < E_NUM; ++e) if (w[e] > best) { best = w[e]; bi = e; }
            int pos = atomicAdd(&counts[bi], 1);
            ltok[bi * M_TOK + pos]  = t;
            lcoef[bi * M_TOK + pos] = best;
            w[bi] = -2.f;
        }
    }
}

__global__ void k_prefix(const int* __restrict__ counts, int* __restrict__ base) {
    if (threadIdx.x == 0) {
        int a = 0;
        for (int e = 0; e < E_NUM; ++e) { base[e] = a; a += counts[e]; }
        base[E_NUM] = a;
    }
}

// ---------------- fp32 -> bf16 conversion of activations ----------------
__global__ __launch_bounds__(256) void k_cvt(const float* __restrict__ x,
                                             unsigned short* __restrict__ xb)
{
    size_t i = ((size_t)blockIdx.x * 256 + threadIdx.x) * 8;
    float4 a = *(const float4*)(x + i);
    float4 b = *(const float4*)(x + i + 4);
    union { unsigned short u[8]; short8 v; } o;
    o.u[0] = f2bf(a.x); o.u[1] = f2bf(a.y); o.u[2] = f2bf(a.z); o.u[3] = f2bf(a.w);
    o.u[4] = f2bf(b.x); o.u[5] = f2bf(b.y); o.u[6] = f2bf(b.z); o.u[7] = f2bf(b.w);
    *(short8*)(xb + i) = o.v;
}

// ---------------- generic bf16 MFMA GEMM ----------------
// MODE 0: shared up   (A=xb direct,  dual-B silu·mul -> hs bf16)
// MODE 1: shared down (A=hs direct,  single-B, out = fp32 * sg[token])
// MODE 2: expert up   (A=xb gathered, dual-B silu·mul -> he bf16, masked)
// MODE 3: expert down (A=he rows base+r, single-B, atomicAdd out * coef, masked)
// Tile: BM=128 x BN, BK=64, 256 threads (4 waves, 2x2), 16x16x32 bf16 MFMA.
template<int MODE, int BN, int KDIM, int NOFF, int OSTR, long long BSTR>
__global__ __launch_bounds__(256) void k_gemm(
    const unsigned short* __restrict__ Abase,
    const float* __restrict__ Bbase,
    void* __restrict__ outp,
    const int* __restrict__ ltok, const float* __restrict__ lcoef,
    const int* __restrict__ counts, const int* __restrict__ basearr,
    const float* __restrict__ sg)
{
    constexpr bool DUAL = (MODE == 0 || MODE == 2);
    constexpr int NFR = BN / 32;           // n-frags per wave

    const int tid = threadIdx.x;
    const int lane = tid & 63, wid = tid >> 6;
    const int wr = wid >> 1, wc = wid & 1;
    const int lr = lane & 15, lk = lane >> 4;
    const int n0 = blockIdx.x * BN;
    const int r0 = blockIdx.y * 128;
    const int e = blockIdx.z;

    int cnt = M_TOK, gbase = 0;
    if constexpr (MODE == 2 || MODE == 3) {
        cnt = counts[e];
        if (r0 >= cnt) return;
        gbase = basearr[e];
    }
    const float* Bexp = Bbase + (size_t)e * (size_t)BSTR;

    __shared__ unsigned short sA[128 * 64];
    __shared__ unsigned short sB[128 * 64];

    f32x4 acc[4][NFR];
    f32x4 accu[4][NFR];
    const f32x4 z = {0.f, 0.f, 0.f, 0.f};
#pragma unroll
    for (int m = 0; m < 4; ++m)
#pragma unroll
        for (int n = 0; n < NFR; ++n) { acc[m][n] = z; if constexpr (DUAL) accu[m][n] = z; }

#pragma unroll 1
    for (int kt = 0; kt < KDIM; kt += 64) {
        // ---- stage A: 128x64 bf16 (swizzled) ----
#pragma unroll
        for (int i = 0; i < 4; ++i) {
            int c = i * 256 + tid;
            int row = c >> 3, c8 = c & 7;
            int ar;
            if constexpr (MODE == 0 || MODE == 1) ar = r0 + row;
            else if constexpr (MODE == 2) {
                int rr = r0 + row; if (rr > cnt - 1) rr = cnt - 1;
                ar = ltok[e * M_TOK + rr];
            } else {
                int rr = r0 + row; if (rr > cnt - 1) rr = cnt - 1;
                ar = gbase + rr;
            }
            const unsigned short* src = Abase + (size_t)ar * KDIM + kt + c8 * 8;
            short8 v = *(const short8*)src;
            *(short8*)&sA[(row << 6) + ((c8 ^ (row & 7)) << 3)] = v;
        }
        // ---- stage B: 128x64 fp32 -> bf16 (swizzled) ----
#pragma unroll
        for (int i = 0; i < 4; ++i) {
            int c = i * 256 + tid;
            int row = c >> 3, c8 = c & 7;
            int br;
            if constexpr (DUAL) br = (row >> 6) ? (NOFF + n0 + (row & 63)) : (n0 + (row & 63));
            else br = n0 + row;
            const float* bs = Bexp + (size_t)br * KDIM + kt + c8 * 8;
            float4 f0 = *(const float4*)bs;
            float4 f1 = *(const float4*)(bs + 4);
            union { unsigned short u[8]; short8 v; } o;
            o.u[0] = f2bf(f0.x); o.u[1] = f2bf(f0.y); o.u[2] = f2bf(f0.z); o.u[3] = f2bf(f0.w);
            o.u[4] = f2bf(f1.x); o.u[5] = f2bf(f1.y); o.u[6] = f2bf(f1.z); o.u[7] = f2bf(f1.w);
            *(short8*)&sB[(row << 6) + ((c8 ^ (row & 7)) << 3)] = o.v;
        }
        __syncthreads();
        // ---- MFMA ----
#pragma unroll
        for (int kk = 0; kk < 2; ++kk) {
            const int c8 = kk * 4 + lk;
            short8 af[4];
#pragma unroll
            for (int m = 0; m < 4; ++m) {
                int row = wr * 64 + m * 16 + lr;
                af[m] = *(const short8*)&sA[(row << 6) + ((c8 ^ (row & 7)) << 3)];
            }
#pragma unroll
            for (int n = 0; n < NFR; ++n) {
                int rowb = wc * (BN / 2) + n * 16 + lr;
                short8 bf = *(const short8*)&sB[(rowb << 6) + ((c8 ^ (rowb & 7)) << 3)];
#pragma unroll
                for (int m = 0; m < 4; ++m)
                    acc[m][n] = __builtin_amdgcn_mfma_f32_16x16x32_bf16(af[m], bf, acc[m][n], 0, 0, 0);
                if constexpr (DUAL) {
                    int rowu = rowb + 64;
                    short8 bu = *(const short8*)&sB[(rowu << 6) + ((c8 ^ (rowu & 7)) << 3)];
#pragma unroll
                    for (int m = 0; m < 4; ++m)
                        accu[m][n] = __builtin_amdgcn_mfma_f32_16x16x32_bf16(af[m], bu, accu[m][n], 0, 0, 0);
                }
            }
        }
        __syncthreads();
    }

    // ---- epilogue ----
    const int colbase = n0 + wc * (BN / 2);
#pragma unroll
    for (int m = 0; m < 4; ++m) {
#pragma unroll
        for (int j = 0; j < 4; ++j) {
            const int r = wr * 64 + m * 16 + lk * 4 + j;   // row within tile
            if constexpr (MODE == 0) {
                size_t orow = (size_t)(r0 + r) * IS_DIM;
#pragma unroll
                for (int n = 0; n < NFR; ++n) {
                    int col = colbase + n * 16 + lr;
                    float g = acc[m][n][j];
                    float h = g / (1.f + __expf(-g)) * accu[m][n][j];
                    ((unsigned short*)outp)[orow + col] = f2bf(h);
                }
            } else if constexpr (MODE == 2) {
                if (r0 + r < cnt) {
                    size_t orow = (size_t)(gbase + r0 + r) * I_DIM;
#pragma unroll
                    for (int n = 0; n < NFR; ++n) {
                        int col = colbase + n * 16 + lr;
                        float g = acc[m][n][j];
                        float h = g / (1.f + __expf(-g)) * accu[m][n][j];
                        ((unsigned short*)outp)[orow + col] = f2bf(h);
                    }
                }
            } else if constexpr (MODE == 1) {
                int tok = r0 + r;
                float scale = sg[tok];
                size_t orow = (size_t)tok * H_DIM;
#pragma unroll
                for (int n = 0; n < NFR; ++n) {
                    int col = colbase + n * 16 + lr;
                    ((float*)outp)[orow + col] = acc[m][n][j] * scale;
                }
            } else {
                if (r0 + r < cnt) {
                    int tok = ltok[e * M_TOK + r0 + r];
                    float scale = lcoef[e * M_TOK + r0 + r];
                    size_t orow = (size_t)tok * H_DIM;
#pragma unroll
                    for (int n = 0; n < NFR; ++n) {
                        int col = colbase + n * 16 + lr;
                        atomicAdd((float*)outp + orow + col, acc[m][n][j] * scale);
                    }
                }
            }
        }
    }
}

extern "C" void kernel_launch(void* const* d_in, const int* in_sizes, int n_in,
                              void* d_out, int out_size, void* d_ws, size_t ws_size,
                              hipStream_t stream) {
    const float* x    = (const float*)d_in[0];
    const float* gw   = (const float*)d_in[1];
    const float* sgw  = (const float*)d_in[2];
    const float* w13  = (const float*)d_in[3];
    const float* w2   = (const float*)d_in[4];
    const float* sguw = (const float*)d_in[5];
    const float* sdw  = (const float*)d_in[6];
    float* out = (float*)d_out;

    char* ws = (char*)d_ws;
    unsigned short* xb   = (unsigned short*)(ws);                 // 16,777,216 B
    unsigned short* hbuf = (unsigned short*)(ws + 16777216);      // 46,137,344 B (hs then he)
    int*   ltok   = (int*)  (ws + 62914560);                      // 262,144 B
    float* lcoef  = (float*)(ws + 63176704);                      // 262,144 B
    int*   counts = (int*)  (ws + 63438848);                      // 64 B
    int*   basep  = (int*)  (ws + 63439104);                      // 68 B
    float* sg     = (float*)(ws + 63439360);                      // 16,384 B

    hipMemsetAsync(counts, 0, 64, stream);
    k_router<<<M_TOK / 4, 256, 0, stream>>>(x, gw, sgw, counts, ltok, lcoef, sg);
    k_prefix<<<1, 64, 0, stream>>>(counts, basep);
    k_cvt<<<(M_TOK * H_DIM) / (256 * 8), 256, 0, stream>>>(x, xb);

    // shared up: [4096,2048] x [11264,2048]^T -> silu·mul -> hs bf16 [4096,5632]
    k_gemm<0, 64, 2048, 5632, 5632, 0>
        <<<dim3(IS_DIM / 64, M_TOK / 128, 1), 256, 0, stream>>>(
            xb, sguw, hbuf, ltok, lcoef, counts, basep, sg);
    // shared down: hs x [2048,5632]^T * sg -> out fp32 [4096,2048]
    k_gemm<1, 128, 5632, 0, 2048, 0>
        <<<dim3(H_DIM / 128, M_TOK / 128, 1), 256, 0, stream>>>(
            hbuf, sdw, out, ltok, lcoef, counts, basep, sg);
    // expert up (gathered): xb x w13_e^T -> silu·mul -> he bf16 [16384,1408]
    k_gemm<2, 64, 2048, 1408, 1408, 5767168LL>
        <<<dim3(I_DIM / 64, M_TOK / 128, E_NUM), 256, 0, stream>>>(
            xb, w13, hbuf, ltok, lcoef, counts, basep, sg);
    // expert down: he x w2_e^T * coef -> atomicAdd out
    k_gemm<3, 128, 1408, 0, 2048, 2883584LL>
        <<<dim3(H_DIM / 128, M_TOK / 128, E_NUM), 256, 0, stream>>>(
            hbuf, w2, out, ltok, lcoef, counts, basep, sg);
}

// Round 2
// 1336.767 us; speedup vs baseline: 1.0422x; 1.0422x over previous
//
#include <hip/hip_runtime.h>
#include <hip/hip_bf16.h>

// ---- problem constants ----
#define E_NUM 16
#define TOPK 4
#define H_DIM 2048
#define I_DIM 1408
#define IS_DIM 5632
#define M_TOK 4096

typedef __attribute__((ext_vector_type(8))) short short8;
typedef __attribute__((ext_vector_type(4))) float f32x4;

static __device__ __forceinline__ unsigned short f2bf(float f) {
    unsigned int u = __float_as_uint(f);
    unsigned int r = (u + 0x7FFFu + ((u >> 16) & 1u)) >> 16;
    return (unsigned short)r;
}

static __device__ __forceinline__ void gl16(const unsigned short* g, unsigned short* l) {
    __builtin_amdgcn_global_load_lds(
        (const __attribute__((address_space(1))) unsigned int*)g,
        (__attribute__((address_space(3))) unsigned int*)l, 16, 0, 0);
}

// ---------------- router: fp32 logits, softmax, top-4, shared gate ----------------
__global__ __launch_bounds__(256) void k_router(
    const float* __restrict__ x, const float* __restrict__ gw,
    const float* __restrict__ sgw, int* __restrict__ counts,
    int* __restrict__ ltok, float* __restrict__ lcoef, float* __restrict__ sg)
{
    const int wid = threadIdx.x >> 6, lane = threadIdx.x & 63;
    const int t = blockIdx.x * 4 + wid;
    const float* xr = x + (size_t)t * H_DIM;
    float xv[32];
#pragma unroll
    for (int i = 0; i < 32; ++i) xv[i] = xr[i * 64 + lane];

    float lg[E_NUM];
    for (int e = 0; e < E_NUM; ++e) {
        const float* g = gw + (size_t)e * H_DIM;
        float s = 0.f;
#pragma unroll
        for (int i = 0; i < 32; ++i) s += xv[i] * g[i * 64 + lane];
#pragma unroll
        for (int off = 32; off; off >>= 1) s += __shfl_xor(s, off);
        lg[e] = s;
    }
    {   // shared expert gate (sigmoid)
        float s = 0.f;
#pragma unroll
        for (int i = 0; i < 32; ++i) s += xv[i] * sgw[i * 64 + lane];
#pragma unroll
        for (int off = 32; off; off >>= 1) s += __shfl_xor(s, off);
        if (lane == 0) sg[t] = 1.f / (1.f + __expf(-s));
    }
    float mx = lg[0];
#pragma unroll
    for (int e = 1; e < E_NUM; ++e) mx = fmaxf(mx, lg[e]);
    float sum = 0.f, w[E_NUM];
#pragma unroll
    for (int e = 0; e < E_NUM; ++e) { w[e] = __expf(lg[e] - mx); sum += w[e]; }
    float inv = 1.f / sum;
#pragma unroll
    for (int e = 0; e < E_NUM; ++e) w[e] *= inv;

    if (lane == 0) {
        for (int j = 0; j < TOPK; ++j) {
            float best = -1.f; int bi = 0;
            for (int e = 0; e < E_NUM; ++e) if (w[e] > best) { best = w[e]; bi = e; }
            int pos = atomicAdd(&counts[bi], 1);
            ltok[bi * M_TOK + pos]  = t;
            lcoef[bi * M_TOK + pos] = best;
            w[bi] = -2.f;
        }
    }
}

__global__ void k_prefix(const int* __restrict__ counts, int* __restrict__ base) {
    if (threadIdx.x == 0) {
        int a = 0;
        for (int e = 0; e < E_NUM; ++e) { base[e] = a; a += counts[e]; }
        base[E_NUM] = a;
    }
}

// ---------------- fp32 -> bf16 conversion (grid-stride, 8 elems/thread) ----------------
__global__ __launch_bounds__(256) void k_cvtw(const float* __restrict__ src,
                                              unsigned short* __restrict__ dst, size_t n8)
{
    size_t stride = (size_t)gridDim.x * 256;
    for (size_t t = (size_t)blockIdx.x * 256 + threadIdx.x; t < n8; t += stride) {
        size_t i = t * 8;
        float4 a = *(const float4*)(src + i);
        float4 b = *(const float4*)(src + i + 4);
        union { unsigned short u[8]; short8 v; } o;
        o.u[0] = f2bf(a.x); o.u[1] = f2bf(a.y); o.u[2] = f2bf(a.z); o.u[3] = f2bf(a.w);
        o.u[4] = f2bf(b.x); o.u[5] = f2bf(b.y); o.u[6] = f2bf(b.z); o.u[7] = f2bf(b.w);
        *(short8*)(dst + i) = o.v;
    }
}

// ---------------- generic bf16 MFMA GEMM ----------------
// MODE 0: shared up   (A=xb,  dual-B silu·mul -> hs bf16)
// MODE 1: shared down (A=hs,  single-B, out = fp32 * sg[token])
// MODE 2: expert up   (A=xb gathered, dual-B silu·mul -> he bf16, masked)
// MODE 3: expert down (A=he rows base+r, single-B, atomicAdd out * coef, masked)
// BCVT: B already bf16 -> global_load_lds staging (pre-swizzled source);
//       else B fp32 -> reg-cvt staging (swizzled ds_write).
// Tile: 128 x BN, BK=64, 256 threads (4 waves 2x2), 16x16x32 bf16 MFMA.
template<int MODE, int BN, int KDIM, int NOFF, long long BSTR, bool BCVT>
__global__ __launch_bounds__(256) void k_gemm(
    const unsigned short* __restrict__ Abase,
    const void* __restrict__ Bvoid,
    void* __restrict__ outp,
    const int* __restrict__ ltok, const float* __restrict__ lcoef,
    const int* __restrict__ counts, const int* __restrict__ basearr,
    const float* __restrict__ sg)
{
    constexpr bool DUAL = (MODE == 0 || MODE == 2);
    constexpr int NFR = BN / 32;

    const int tid = threadIdx.x;
    const int lane = tid & 63, wid = tid >> 6;
    const int wr = wid >> 1, wc = wid & 1;
    const int lr = lane & 15, lk = lane >> 4;
    const int n0 = blockIdx.x * BN;
    const int r0 = blockIdx.y * 128;
    const int e = blockIdx.z;

    int cnt = M_TOK, gbase = 0;
    if constexpr (MODE == 2 || MODE == 3) {
        cnt = counts[e];
        if (r0 >= cnt) return;
        gbase = basearr[e];
    }

    __shared__ unsigned short sA[128 * 64];
    __shared__ unsigned short sB[128 * 64];

    // ---- staging source pointers (fixed per thread across K) ----
    const int srow = lane >> 3, sc8 = lane & 7;
    const unsigned short* aptr[4];
#pragma unroll
    for (int i = 0; i < 4; ++i) {
        const int row = (i * 4 + wid) * 8 + srow;
        int ar;
        if constexpr (MODE == 0 || MODE == 1) ar = r0 + row;
        else if constexpr (MODE == 2) {
            int rr = r0 + row; if (rr > cnt - 1) rr = cnt - 1;
            ar = ltok[e * M_TOK + rr];
        } else {
            int rr = r0 + row; if (rr > cnt - 1) rr = cnt - 1;
            ar = gbase + rr;
        }
        aptr[i] = Abase + (size_t)ar * KDIM + ((sc8 ^ (row & 7)) << 3);
    }
    const unsigned short* bptr[4];
    const float* Bf = nullptr;
    if constexpr (BCVT) {
        const unsigned short* Bx = (const unsigned short*)Bvoid + (size_t)e * (size_t)BSTR;
#pragma unroll
        for (int i = 0; i < 4; ++i) {
            const int row = (i * 4 + wid) * 8 + srow;
            int br;
            if constexpr (DUAL) br = (row >= 64) ? (NOFF + n0 + row - 64) : (n0 + row);
            else br = n0 + row;
            bptr[i] = Bx + (size_t)br * KDIM + ((sc8 ^ (row & 7)) << 3);
        }
    } else {
        Bf = (const float*)Bvoid + (size_t)e * (size_t)BSTR;
    }

    f32x4 acc[4][NFR];
    f32x4 accu[4][NFR];
    const f32x4 z = {0.f, 0.f, 0.f, 0.f};
#pragma unroll
    for (int m = 0; m < 4; ++m)
#pragma unroll
        for (int n = 0; n < NFR; ++n) { acc[m][n] = z; if constexpr (DUAL) accu[m][n] = z; }

#pragma unroll 1
    for (int kt = 0; kt < KDIM; kt += 64) {
        // ---- stage A via global_load_lds (linear LDS dest, pre-swizzled source) ----
#pragma unroll
        for (int i = 0; i < 4; ++i)
            gl16(aptr[i] + kt, &sA[(i * 4 + wid) * 512]);
        // ---- stage B ----
        if constexpr (BCVT) {
#pragma unroll
            for (int i = 0; i < 4; ++i)
                gl16(bptr[i] + kt, &sB[(i * 4 + wid) * 512]);
        } else {
#pragma unroll
            for (int i = 0; i < 4; ++i) {
                int c = i * 256 + tid;
                int row = c >> 3, c8 = c & 7;
                int br;
                if constexpr (DUAL) br = (row >= 64) ? (NOFF + n0 + row - 64) : (n0 + row);
                else br = n0 + row;
                const float* bs = Bf + (size_t)br * KDIM + kt + c8 * 8;
                float4 f0 = *(const float4*)bs;
                float4 f1 = *(const float4*)(bs + 4);
                union { unsigned short u[8]; short8 v; } o;
                o.u[0] = f2bf(f0.x); o.u[1] = f2bf(f0.y); o.u[2] = f2bf(f0.z); o.u[3] = f2bf(f0.w);
                o.u[4] = f2bf(f1.x); o.u[5] = f2bf(f1.y); o.u[6] = f2bf(f1.z); o.u[7] = f2bf(f1.w);
                *(short8*)&sB[(row << 6) + ((c8 ^ (row & 7)) << 3)] = o.v;
            }
        }
        __syncthreads();
        // ---- MFMA ----
#pragma unroll
        for (int kk = 0; kk < 2; ++kk) {
            const int c8 = kk * 4 + lk;
            short8 af[4];
#pragma unroll
            for (int m = 0; m < 4; ++m) {
                int row = wr * 64 + m * 16 + lr;
                af[m] = *(const short8*)&sA[(row << 6) + ((c8 ^ (row & 7)) << 3)];
            }
#pragma unroll
            for (int n = 0; n < NFR; ++n) {
                int rowb = wc * (BN / 2) + n * 16 + lr;
                short8 bf = *(const short8*)&sB[(rowb << 6) + ((c8 ^ (rowb & 7)) << 3)];
#pragma unroll
                for (int m = 0; m < 4; ++m)
                    acc[m][n] = __builtin_amdgcn_mfma_f32_16x16x32_bf16(af[m], bf, acc[m][n], 0, 0, 0);
                if constexpr (DUAL) {
                    int rowu = rowb + 64;
                    short8 bu = *(const short8*)&sB[(rowu << 6) + ((c8 ^ (rowu & 7)) << 3)];
#pragma unroll
                    for (int m = 0; m < 4; ++m)
                        accu[m][n] = __builtin_amdgcn_mfma_f32_16x16x32_bf16(af[m], bu, accu[m][n], 0, 0, 0);
                }
            }
        }
        __syncthreads();
    }

    // ---- epilogue ----
    const int colbase = n0 + wc * (BN / 2);
#pragma unroll
    for (int m = 0; m < 4; ++m) {
#pragma unroll
        for (int j = 0; j < 4; ++j) {
            const int r = wr * 64 + m * 16 + lk * 4 + j;
            if constexpr (MODE == 0) {
                size_t orow = (size_t)(r0 + r) * IS_DIM;
#pragma unroll
                for (int n = 0; n < NFR; ++n) {
                    int col = colbase + n * 16 + lr;
                    float g = acc[m][n][j];
                    float h = g / (1.f + __expf(-g)) * accu[m][n][j];
                    ((unsigned short*)outp)[orow + col] = f2bf(h);
                }
            } else if constexpr (MODE == 2) {
                if (r0 + r < cnt) {
                    size_t orow = (size_t)(gbase + r0 + r) * I_DIM;
#pragma unroll
                    for (int n = 0; n < NFR; ++n) {
                        int col = colbase + n * 16 + lr;
                        float g = acc[m][n][j];
                        float h = g / (1.f + __expf(-g)) * accu[m][n][j];
                        ((unsigned short*)outp)[orow + col] = f2bf(h);
                    }
                }
            } else if constexpr (MODE == 1) {
                int tok = r0 + r;
                float scale = sg[tok];
                size_t orow = (size_t)tok * H_DIM;
#pragma unroll
                for (int n = 0; n < NFR; ++n) {
                    int col = colbase + n * 16 + lr;
                    ((float*)outp)[orow + col] = acc[m][n][j] * scale;
                }
            } else {
                if (r0 + r < cnt) {
                    int tok = ltok[e * M_TOK + r0 + r];
                    float scale = lcoef[e * M_TOK + r0 + r];
                    size_t orow = (size_t)tok * H_DIM;
#pragma unroll
                    for (int n = 0; n < NFR; ++n) {
                        int col = colbase + n * 16 + lr;
                        atomicAdd((float*)outp + orow + col, acc[m][n][j] * scale);
                    }
                }
            }
        }
    }
}

extern "C" void kernel_launch(void* const* d_in, const int* in_sizes, int n_in,
                              void* d_out, int out_size, void* d_ws, size_t ws_size,
                              hipStream_t stream) {
    const float* x    = (const float*)d_in[0];
    const float* gw   = (const float*)d_in[1];
    const float* sgw  = (const float*)d_in[2];
    const float* w13  = (const float*)d_in[3];
    const float* w2   = (const float*)d_in[4];
    const float* sguw = (const float*)d_in[5];
    const float* sdw  = (const float*)d_in[6];
    float* out = (float*)d_out;

    char* ws = (char*)d_ws;
    // base buffers (both paths)
    unsigned short* xb   = (unsigned short*)ws;               // 16,777,216 B
    unsigned short* hbuf = (unsigned short*)(ws + 16777216);  // 46,137,344 B (hs then he, sequential reuse)
    // full path: bf16 weight copies
    const bool full = (ws_size >= 409485824ULL);
    unsigned short* w13b  = (unsigned short*)(ws + 62914560);   // 184,549,376 B
    unsigned short* w2b   = (unsigned short*)(ws + 247463936);  //  92,274,688 B
    unsigned short* sguwb = (unsigned short*)(ws + 339738624);  //  46,137,344 B
    unsigned short* sdwb  = (unsigned short*)(ws + 385875968);  //  23,068,672 B
    size_t so = full ? 408944640ULL : 62914560ULL;
    int*   ltok   = (int*)  (ws + so);
    float* lcoef  = (float*)(ws + so + 262144);
    int*   counts = (int*)  (ws + so + 524288);
    int*   basep  = (int*)  (ws + so + 524288 + 256);
    float* sg     = (float*)(ws + so + 524288 + 512);

    hipMemsetAsync(counts, 0, 64, stream);
    k_router<<<M_TOK / 4, 256, 0, stream>>>(x, gw, sgw, counts, ltok, lcoef, sg);
    k_prefix<<<1, 64, 0, stream>>>(counts, basep);
    k_cvtw<<<4096, 256, 0, stream>>>(x, xb, (size_t)M_TOK * H_DIM / 8);

    if (full) {
        k_cvtw<<<8192, 256, 0, stream>>>(sguw, sguwb, (size_t)2 * IS_DIM * H_DIM / 8);
        k_cvtw<<<8192, 256, 0, stream>>>(sdw,  sdwb,  (size_t)H_DIM * IS_DIM / 8);
        k_cvtw<<<8192, 256, 0, stream>>>(w13,  w13b,  (size_t)E_NUM * 2 * I_DIM * H_DIM / 8);
        k_cvtw<<<8192, 256, 0, stream>>>(w2,   w2b,   (size_t)E_NUM * H_DIM * I_DIM / 8);

        k_gemm<0, 64, 2048, IS_DIM, 0, true>
            <<<dim3(IS_DIM / 64, M_TOK / 128, 1), 256, 0, stream>>>(
                xb, sguwb, hbuf, ltok, lcoef, counts, basep, sg);
        k_gemm<1, 128, 5632, 0, 0, true>
            <<<dim3(H_DIM / 128, M_TOK / 128, 1), 256, 0, stream>>>(
                hbuf, sdwb, out, ltok, lcoef, counts, basep, sg);
        k_gemm<2, 64, 2048, I_DIM, 5767168LL, true>
            <<<dim3(I_DIM / 64, M_TOK / 128, E_NUM), 256, 0, stream>>>(
                xb, w13b, hbuf, ltok, lcoef, counts, basep, sg);
        k_gemm<3, 128, 1408, 0, 2883584LL, true>
            <<<dim3(H_DIM / 128, M_TOK / 128, E_NUM), 256, 0, stream>>>(
                hbuf, w2b, out, ltok, lcoef, counts, basep, sg);
    } else {
        k_gemm<0, 64, 2048, IS_DIM, 0, false>
            <<<dim3(IS_DIM / 64, M_TOK / 128, 1), 256, 0, stream>>>(
                xb, sguw, hbuf, ltok, lcoef, counts, basep, sg);
        k_gemm<1, 128, 5632, 0, 0, false>
            <<<dim3(H_DIM / 128, M_TOK / 128, 1), 256, 0, stream>>>(
                hbuf, sdw, out, ltok, lcoef, counts, basep, sg);
        k_gemm<2, 64, 2048, I_DIM, 5767168LL, false>
            <<<dim3(I_DIM / 64, M_TOK / 128, E_NUM), 256, 0, stream>>>(
                xb, w13, hbuf, ltok, lcoef, counts, basep, sg);
        k_gemm<3, 128, 1408, 0, 2883584LL, false>
            <<<dim3(H_DIM / 128, M_TOK / 128, E_NUM), 256, 0, stream>>>(
                hbuf, w2, out, ltok, lcoef, counts, basep, sg);
    }
}

// Round 3
// 1215.311 us; speedup vs baseline: 1.1464x; 1.0999x over previous
//
#include <hip/hip_runtime.h>
#include <hip/hip_bf16.h>

// ---- problem constants ----
#define E_NUM 16
#define TOPK 4
#define H_DIM 2048
#define I_DIM 1408
#define IS_DIM 5632
#define M_TOK 4096

typedef __attribute__((ext_vector_type(8))) short short8;
typedef __attribute__((ext_vector_type(4))) float f32x4;

static __device__ __forceinline__ unsigned short f2bf(float f) {
    unsigned int u = __float_as_uint(f);
    unsigned int r = (u + 0x7FFFu + ((u >> 16) & 1u)) >> 16;
    return (unsigned short)r;
}

static __device__ __forceinline__ void gl16(const unsigned short* g, unsigned short* l) {
    __builtin_amdgcn_global_load_lds(
        (const __attribute__((address_space(1))) unsigned int*)g,
        (__attribute__((address_space(3))) unsigned int*)l, 16, 0, 0);
}

// ---------------- router: fp32 logits, softmax, top-4, shared gate ----------------
__global__ __launch_bounds__(256) void k_router(
    const float* __restrict__ x, const float* __restrict__ gw,
    const float* __restrict__ sgw, int* __restrict__ counts,
    int* __restrict__ ltok, float* __restrict__ lcoef, float* __restrict__ sg)
{
    const int wid = threadIdx.x >> 6, lane = threadIdx.x & 63;
    const int t = blockIdx.x * 4 + wid;
    const float* xr = x + (size_t)t * H_DIM;
    float xv[32];
#pragma unroll
    for (int i = 0; i < 32; ++i) xv[i] = xr[i * 64 + lane];

    float lg[E_NUM];
    for (int e = 0; e < E_NUM; ++e) {
        const float* g = gw + (size_t)e * H_DIM;
        float s = 0.f;
#pragma unroll
        for (int i = 0; i < 32; ++i) s += xv[i] * g[i * 64 + lane];
#pragma unroll
        for (int off = 32; off; off >>= 1) s += __shfl_xor(s, off);
        lg[e] = s;
    }
    {
        float s = 0.f;
#pragma unroll
        for (int i = 0; i < 32; ++i) s += xv[i] * sgw[i * 64 + lane];
#pragma unroll
        for (int off = 32; off; off >>= 1) s += __shfl_xor(s, off);
        if (lane == 0) sg[t] = 1.f / (1.f + __expf(-s));
    }
    float mx = lg[0];
#pragma unroll
    for (int e = 1; e < E_NUM; ++e) mx = fmaxf(mx, lg[e]);
    float sum = 0.f, w[E_NUM];
#pragma unroll
    for (int e = 0; e < E_NUM; ++e) { w[e] = __expf(lg[e] - mx); sum += w[e]; }
    float inv = 1.f / sum;
#pragma unroll
    for (int e = 0; e < E_NUM; ++e) w[e] *= inv;

    if (lane == 0) {
        for (int j = 0; j < TOPK; ++j) {
            float best = -1.f; int bi = 0;
            for (int e = 0; e < E_NUM; ++e) if (w[e] > best) { best = w[e]; bi = e; }
            int pos = atomicAdd(&counts[bi], 1);
            ltok[bi * M_TOK + pos]  = t;
            lcoef[bi * M_TOK + pos] = best;
            w[bi] = -2.f;
        }
    }
}

__global__ void k_prefix(const int* __restrict__ counts, int* __restrict__ base) {
    if (threadIdx.x == 0) {
        int a = 0;
        for (int e = 0; e < E_NUM; ++e) { base[e] = a; a += counts[e]; }
        base[E_NUM] = a;
    }
}

// ---------------- fp32 -> bf16 conversion (grid-stride, 8 elems/thread) ----------------
__global__ __launch_bounds__(256) void k_cvtw(const float* __restrict__ src,
                                              unsigned short* __restrict__ dst, size_t n8)
{
    size_t stride = (size_t)gridDim.x * 256;
    for (size_t t = (size_t)blockIdx.x * 256 + threadIdx.x; t < n8; t += stride) {
        size_t i = t * 8;
        float4 a = *(const float4*)(src + i);
        float4 b = *(const float4*)(src + i + 4);
        union { unsigned short u[8]; short8 v; } o;
        o.u[0] = f2bf(a.x); o.u[1] = f2bf(a.y); o.u[2] = f2bf(a.z); o.u[3] = f2bf(a.w);
        o.u[4] = f2bf(b.x); o.u[5] = f2bf(b.y); o.u[6] = f2bf(b.z); o.u[7] = f2bf(b.w);
        *(short8*)(dst + i) = o.v;
    }
}

// ---------------- 256-tile double-buffered 2-phase bf16 MFMA GEMM ----------------
// MODE 0: shared up   (A=xb,  dual-B silu·mul -> hs bf16)          BN=128
// MODE 1: shared down (A=hs,  single-B, atomicAdd out*sg, K-split) BN=256
// MODE 2: expert up   (A=xb gathered, dual-B silu·mul -> he)       BN=128
// MODE 3: expert down (A=he, single-B, atomicAdd out*coef)         BN=256
// BM=256, BK=64, 512 threads (8 waves, 2Mx4N), dbuf LDS 128 KiB.
// LDS layout identical to verified rounds: row-major [row][64] with
// c8 ^= (row&7) swizzle; gload_lds uses linear dest + pre-swizzled source.
template<int MODE, int BN, int KDIM, int NOFF, long long BSTR, int KSPLIT>
__global__ __launch_bounds__(512, 2) void k_gemm(
    const unsigned short* __restrict__ Abase,
    const unsigned short* __restrict__ Bbase,
    void* __restrict__ outp,
    const int* __restrict__ ltok, const float* __restrict__ lcoef,
    const int* __restrict__ counts, const int* __restrict__ basearr,
    const float* __restrict__ sg)
{
    constexpr bool DUAL = (MODE == 0 || MODE == 2);
    constexpr int NFR = BN / 64;          // B-frags per wave per kk
    constexpr int KCH = KDIM / KSPLIT;    // K range per z (MODE 1 split)

    extern __shared__ unsigned short smem[];
    unsigned short* sA = smem;            // [2][256*64]
    unsigned short* sB = smem + 32768;    // [2][256*64]

    const int tid = threadIdx.x;
    const int lane = tid & 63, wid = tid >> 6;
    const int wr = wid >> 2, wcol = wid & 3;
    const int lr = lane & 15, lk = lane >> 4;

    // ---- bijective XCD-chunk swizzle over (x,y), y-major within chunk ----
    const unsigned gx = gridDim.x, gy = gridDim.y;
    const unsigned nwg = gx * gy;
    const unsigned orig = blockIdx.y * gx + blockIdx.x;   // HW dispatch order (x fastest)
    const unsigned q8 = nwg >> 3, r8 = nwg & 7;
    const unsigned xcd = orig & 7, off8 = orig >> 3;
    const unsigned wg = ((xcd < r8) ? xcd * (q8 + 1) : r8 * (q8 + 1) + (xcd - r8) * q8) + off8;
    const int n0 = (int)(wg / gy) * BN;
    const int r0 = (int)(wg % gy) * 256;
    const int e  = blockIdx.z;

    int cnt = M_TOK, gbase = 0;
    if constexpr (MODE == 2 || MODE == 3) {
        cnt = counts[e];
        if (r0 >= cnt) return;
        gbase = basearr[e];
    }
    const int kbeg = (KSPLIT > 1) ? e * KCH : 0;
    const unsigned short* Bexp = Bbase + (size_t)e * (size_t)BSTR;

    // ---- per-thread staging source pointers (pre-swizzled, fixed across K) ----
    const unsigned short* aptr[4];
    const unsigned short* bptr[4];
#pragma unroll
    for (int i = 0; i < 4; ++i) {
        const int c = i * 512 + tid;
        const int row = c >> 3, c8 = c & 7;
        int ar;
        if constexpr (MODE == 0 || MODE == 1) ar = r0 + row;
        else {
            int rr = r0 + row; if (rr > cnt - 1) rr = cnt - 1;
            ar = (MODE == 2) ? ltok[e * M_TOK + rr] : (gbase + rr);
        }
        aptr[i] = Abase + (size_t)ar * KDIM + kbeg + ((c8 ^ (row & 7)) << 3);
        int br;
        if constexpr (DUAL) br = (row < 128) ? (n0 + row) : (NOFF + n0 + row - 128);
        else br = n0 + row;
        bptr[i] = Bexp + (size_t)br * KDIM + kbeg + ((c8 ^ (row & 7)) << 3);
    }

    f32x4 acc[8][NFR];
    f32x4 accu[DUAL ? 8 : 1][NFR];
    const f32x4 z = {0.f, 0.f, 0.f, 0.f};
#pragma unroll
    for (int m = 0; m < 8; ++m)
#pragma unroll
        for (int n = 0; n < NFR; ++n) { acc[m][n] = z; if constexpr (DUAL) accu[m][n] = z; }

    auto STAGE = [&](int buf, int kt) {
        const int bo = buf << 14;
#pragma unroll
        for (int i = 0; i < 4; ++i) gl16(aptr[i] + kt, &sA[bo + ((i * 512 + tid) << 3)]);
#pragma unroll
        for (int i = 0; i < 4; ++i) gl16(bptr[i] + kt, &sB[bo + ((i * 512 + tid) << 3)]);
    };

    STAGE(0, 0);
    __syncthreads();
    int cur = 0;
#pragma unroll 1
    for (int kt = 0; kt < KCH; kt += 64) {
        if (kt + 64 < KCH) STAGE(cur ^ 1, kt + 64);   // prefetch next tile
        __builtin_amdgcn_s_setprio(1);
#pragma unroll
        for (int kk = 0; kk < 2; ++kk) {
            const int c8 = kk * 4 + lk;
            short8 af[8];
#pragma unroll
            for (int m = 0; m < 8; ++m) {
                const int row = wr * 128 + m * 16 + lr;
                af[m] = *(const short8*)&sA[(cur << 14) + (row << 6) + ((c8 ^ (row & 7)) << 3)];
            }
#pragma unroll
            for (int n = 0; n < NFR; ++n) {
                const int rowb = wcol * (BN / 4) + n * 16 + lr;
                short8 bf = *(const short8*)&sB[(cur << 14) + (rowb << 6) + ((c8 ^ (rowb & 7)) << 3)];
#pragma unroll
                for (int m = 0; m < 8; ++m)
                    acc[m][n] = __builtin_amdgcn_mfma_f32_16x16x32_bf16(af[m], bf, acc[m][n], 0, 0, 0);
                if constexpr (DUAL) {
                    const int rowu = rowb + 128;
                    short8 bu = *(const short8*)&sB[(cur << 14) + (rowu << 6) + ((c8 ^ (rowu & 7)) << 3)];
#pragma unroll
                    for (int m = 0; m < 8; ++m)
                        accu[m][n] = __builtin_amdgcn_mfma_f32_16x16x32_bf16(af[m], bu, accu[m][n], 0, 0, 0);
                }
            }
        }
        __builtin_amdgcn_s_setprio(0);
        __syncthreads();   // vmcnt(0)+lgkmcnt(0)+barrier: prefetch landed, reads done
        cur ^= 1;
    }

    // ---- epilogue ----
    const int colbase = n0 + wcol * (BN / 4);
#pragma unroll
    for (int m = 0; m < 8; ++m) {
#pragma unroll
        for (int j = 0; j < 4; ++j) {
            const int r = wr * 128 + m * 16 + lk * 4 + j;
            if constexpr (MODE == 0) {
                size_t orow = (size_t)(r0 + r) * IS_DIM;
#pragma unroll
                for (int n = 0; n < NFR; ++n) {
                    int col = colbase + n * 16 + lr;
                    float g = acc[m][n][j];
                    float h = g / (1.f + __expf(-g)) * accu[m][n][j];
                    ((unsigned short*)outp)[orow + col] = f2bf(h);
                }
            } else if constexpr (MODE == 2) {
                if (r0 + r < cnt) {
                    size_t orow = (size_t)(gbase + r0 + r) * I_DIM;
#pragma unroll
                    for (int n = 0; n < NFR; ++n) {
                        int col = colbase + n * 16 + lr;
                        float g = acc[m][n][j];
                        float h = g / (1.f + __expf(-g)) * accu[m][n][j];
                        ((unsigned short*)outp)[orow + col] = f2bf(h);
                    }
                }
            } else if constexpr (MODE == 1) {
                int tok = r0 + r;
                float scale = sg[tok];
                size_t orow = (size_t)tok * H_DIM;
#pragma unroll
                for (int n = 0; n < NFR; ++n) {
                    int col = colbase + n * 16 + lr;
                    atomicAdd((float*)outp + orow + col, acc[m][n][j] * scale);
                }
            } else {
                if (r0 + r < cnt) {
                    int tok = ltok[e * M_TOK + r0 + r];
                    float scale = lcoef[e * M_TOK + r0 + r];
                    size_t orow = (size_t)tok * H_DIM;
#pragma unroll
                    for (int n = 0; n < NFR; ++n) {
                        int col = colbase + n * 16 + lr;
                        atomicAdd((float*)outp + orow + col, acc[m][n][j] * scale);
                    }
                }
            }
        }
    }
}

extern "C" void kernel_launch(void* const* d_in, const int* in_sizes, int n_in,
                              void* d_out, int out_size, void* d_ws, size_t ws_size,
                              hipStream_t stream) {
    const float* x    = (const float*)d_in[0];
    const float* gw   = (const float*)d_in[1];
    const float* sgw  = (const float*)d_in[2];
    const float* w13  = (const float*)d_in[3];
    const float* w2   = (const float*)d_in[4];
    const float* sguw = (const float*)d_in[5];
    const float* sdw  = (const float*)d_in[6];
    float* out = (float*)d_out;

    char* ws = (char*)d_ws;
    unsigned short* xb    = (unsigned short*)ws;                // 16,777,216 B
    unsigned short* hbuf  = (unsigned short*)(ws + 16777216);   // 46,137,344 B (hs then he)
    unsigned short* w13b  = (unsigned short*)(ws + 62914560);   // 184,549,376 B
    unsigned short* w2b   = (unsigned short*)(ws + 247463936);  //  92,274,688 B
    unsigned short* sguwb = (unsigned short*)(ws + 339738624);  //  46,137,344 B
    unsigned short* sdwb  = (unsigned short*)(ws + 385875968);  //  23,068,672 B
    size_t so = 408944640ULL;
    int*   ltok   = (int*)  (ws + so);
    float* lcoef  = (float*)(ws + so + 262144);
    int*   counts = (int*)  (ws + so + 524288);
    int*   basep  = (int*)  (ws + so + 524288 + 256);
    float* sg     = (float*)(ws + so + 524288 + 512);

    hipMemsetAsync(counts, 0, 64, stream);
    hipMemsetAsync(out, 0, (size_t)out_size * sizeof(float), stream);
    k_router<<<M_TOK / 4, 256, 0, stream>>>(x, gw, sgw, counts, ltok, lcoef, sg);
    k_prefix<<<1, 64, 0, stream>>>(counts, basep);
    k_cvtw<<<4096, 256, 0, stream>>>(x, xb, (size_t)M_TOK * H_DIM / 8);
    k_cvtw<<<8192, 256, 0, stream>>>(sguw, sguwb, (size_t)2 * IS_DIM * H_DIM / 8);
    k_cvtw<<<8192, 256, 0, stream>>>(sdw,  sdwb,  (size_t)H_DIM * IS_DIM / 8);
    k_cvtw<<<8192, 256, 0, stream>>>(w13,  w13b,  (size_t)E_NUM * 2 * I_DIM * H_DIM / 8);
    k_cvtw<<<8192, 256, 0, stream>>>(w2,   w2b,   (size_t)E_NUM * H_DIM * I_DIM / 8);

    static const int DYN = 131072;
    (void)hipFuncSetAttribute(reinterpret_cast<const void*>(&k_gemm<0, 128, 2048, IS_DIM, 0LL, 1>),
                              hipFuncAttributeMaxDynamicSharedMemorySize, DYN);
    (void)hipFuncSetAttribute(reinterpret_cast<const void*>(&k_gemm<1, 256, 5632, 0, 0LL, 2>),
                              hipFuncAttributeMaxDynamicSharedMemorySize, DYN);
    (void)hipFuncSetAttribute(reinterpret_cast<const void*>(&k_gemm<2, 128, 2048, I_DIM, 5767168LL, 1>),
                              hipFuncAttributeMaxDynamicSharedMemorySize, DYN);
    (void)hipFuncSetAttribute(reinterpret_cast<const void*>(&k_gemm<3, 256, 1408, 0, 2883584LL, 1>),
                              hipFuncAttributeMaxDynamicSharedMemorySize, DYN);

    // shared up: xb[4096,2048] x sguwb^T (dual) -> silu·mul -> hs bf16 [4096,5632]
    k_gemm<0, 128, 2048, IS_DIM, 0LL, 1>
        <<<dim3(IS_DIM / 128, M_TOK / 256, 1), 512, DYN, stream>>>(
            xb, sguwb, hbuf, ltok, lcoef, counts, basep, sg);
    // shared down (split-K=2): hs x sdwb^T * sg -> atomicAdd out
    k_gemm<1, 256, 5632, 0, 0LL, 2>
        <<<dim3(H_DIM / 256, M_TOK / 256, 2), 512, DYN, stream>>>(
            hbuf, sdwb, out, ltok, lcoef, counts, basep, sg);
    // expert up (gathered): xb x w13b_e^T (dual) -> silu·mul -> he bf16 [16384,1408]
    k_gemm<2, 128, 2048, I_DIM, 5767168LL, 1>
        <<<dim3(I_DIM / 128, M_TOK / 256, E_NUM), 512, DYN, stream>>>(
            xb, w13b, hbuf, ltok, lcoef, counts, basep, sg);
    // expert down: he x w2b_e^T * coef -> atomicAdd out
    k_gemm<3, 256, 1408, 0, 2883584LL, 1>
        <<<dim3(H_DIM / 256, M_TOK / 256, E_NUM), 512, DYN, stream>>>(
            hbuf, w2b, out, ltok, lcoef, counts, basep, sg);
}